// Round 8
// baseline (300.302 us; speedup 1.0000x reference)
//
#include <hip/hip_runtime.h>
#include <cstdint>
#include <cstddef>

// (B,H,S,Dh) = (2, 8, 2048, 64), all float32 in/out.
#define BB 2
#define HH 8
#define SS 2048
#define DD 64
#define KP 128                 // bf16 hi|lo concatenated along k-dim
#define QT 32                  // q rows per WG
#define KSPLIT 8
#define KRANGE (SS / KSPLIT)   // 256 kv per WG
#define CKV 32                 // kv per chunk (two MFMA tiles wide)
#define NCH (KRANGE / CKV)     // 8 chunks
#define LROW (CKV + 1)         // padded LDS row stride (u32)
#define PLSTR (QT * LROW)      // LDS plane stride (u32) = 1056
#define BUFSTR (4 * PLSTR)     // LDS buffer stride (u32) = 4224
#define NROWS (BB * HH * SS)   // 32768 (b,h,row) triples

typedef short short8 __attribute__((ext_vector_type(8)));
typedef float f32x4  __attribute__((ext_vector_type(4)));
using u16 = unsigned short;
using u32 = unsigned int;
using u8  = unsigned char;

__device__ inline u16 bf16_rne(float f) {
  u32 u = __builtin_bit_cast(u32, f);
  u32 r = (u + 0x7FFFu + ((u >> 16) & 1u)) >> 16;
  return (u16)r;
}
__device__ inline float bf16_to_f(u16 h) {
  u32 u = ((u32)h) << 16;
  return __builtin_bit_cast(float, u);
}
__device__ inline u32 pack_bf16(float a, float b) {
  return (u32)bf16_rne(a) | ((u32)bf16_rne(b) << 16);
}

// Barrier draining ONLY the LDS queue — __syncthreads would also drain
// vmcnt(0), killing the in-flight HBM bias / L2 k prefetches (m97 drain).
// sched_barrier(0) pins code motion (rule #18).
__device__ __forceinline__ void lds_barrier() {
  __builtin_amdgcn_sched_barrier(0);
  asm volatile("s_waitcnt lgkmcnt(0)" ::: "memory");
  __builtin_amdgcn_s_barrier();
  __builtin_amdgcn_sched_barrier(0);
}

// ---------------- K_mask: canonicalize mask -> u8[B*S] ---------------------
__global__ __launch_bounds__(256) void mask_canon(
    const void* __restrict__ maskg, u8* __restrict__ mc)
{
  __shared__ int sf, su;
  const int t = (int)threadIdx.x;
  if (t == 0) { sf = 0; su = 0; }
  __syncthreads();
  const u32* mw = (const u32*)maskg;
  int f = 0, u = 0;
  for (int i = t; i < 1024; i += 256) {   // 4KB scan: valid for all encodings
    u32 w = mw[i];
    if (w == 0x3F800000u) f = 1;
    if (w > 1u && w != 0x3F800000u) u = 1;
  }
  if (f) sf = 1;
  if (u) su = 1;
  __syncthreads();
  const int mode = sf ? 2 : (su ? 1 : 0);
  for (int i = t; i < BB * SS; i += 256) {
    u8 m;
    if (mode == 2)      m = (((const float*)maskg)[i] != 0.0f) ? 1 : 0;
    else if (mode == 1) m = (((const u8*)maskg)[i] != 0) ? 1 : 0;
    else                m = (((const int*)maskg)[i] != 0) ? 1 : 0;
    mc[i] = m;
  }
}

// ---------------- K0: f32 -> bf16 hi|lo (K=64 -> K=128) --------------------
__global__ __launch_bounds__(256) void convert_kernel(
    const float* __restrict__ q, const float* __restrict__ k,
    u16* __restrict__ qw, u16* __restrict__ kw)
{
  const int i   = (int)(blockIdx.x * 256 + threadIdx.x);  // float4 index
  const int row = i >> 4;
  const int c4  = (i & 15) << 2;

  const float4 qv = *(const float4*)(q + (size_t)i * 4);
  const float4 kv = *(const float4*)(k + (size_t)i * 4);

  u16 qh[4], ql[4], kh[4], kl[4];
  {
    const float qa[4] = {qv.x, qv.y, qv.z, qv.w};
    const float ka[4] = {kv.x, kv.y, kv.z, kv.w};
#pragma unroll
    for (int j = 0; j < 4; ++j) {
      qh[j] = bf16_rne(qa[j]);
      ql[j] = bf16_rne(qa[j] - bf16_to_f(qh[j]));
      kh[j] = bf16_rne(ka[j]);
      kl[j] = bf16_rne(ka[j] - bf16_to_f(kh[j]));
    }
  }

  uint2 qhi, qlo, khi, klo;
  qhi.x = (u32)qh[0] | ((u32)qh[1] << 16); qhi.y = (u32)qh[2] | ((u32)qh[3] << 16);
  qlo.x = (u32)ql[0] | ((u32)ql[1] << 16); qlo.y = (u32)ql[2] | ((u32)ql[3] << 16);
  khi.x = (u32)kh[0] | ((u32)kh[1] << 16); khi.y = (u32)kh[2] | ((u32)kh[3] << 16);
  klo.x = (u32)kl[0] | ((u32)kl[1] << 16); klo.y = (u32)kl[2] | ((u32)kl[3] << 16);

  const size_t base = (size_t)row * KP + c4;
  *(uint2*)(qw + base)      = qhi;
  *(uint2*)(qw + base + DD) = qlo;
  *(uint2*)(kw + base)      = khi;
  *(uint2*)(kw + base + DD) = klo;
}

// ---------------- K1: scores + bias + exp -> w' (unnormalized) -------------
// WG = 512 = 8 waves = 8 heads, same (b, q-tile 32, kv-range 256).
// Software pipelines (per 32-kv chunk, 8 chunks, ONE lgkm barrier each):
//   k-frags:  LOADK(c+1) issued right after MFMA(c) consumes the regs
//   bias:     LOADB(c+2) -> regs -> STAGEB(c+1) -> LDS (bf16, pad-33 rows)
__global__ __launch_bounds__(512, 4) void score_kernel(
    const u16* __restrict__ qw, const u16* __restrict__ kw,
    const float* __restrict__ scaleg, const u8* __restrict__ maskc,
    const float* __restrict__ biasg, float* __restrict__ outg)
{
  __shared__ u32 s_b32[2 * BUFSTR];   // 33.8 KB: [buf][plane h/2][qr][kv pad33]
  __shared__ u8  s_mask[KRANGE];

  const int t    = (int)threadIdx.x;
  const int wid  = t >> 6;        // wave = head
  const int lane = t & 63;
  const int l15  = lane & 15;
  const int l4   = lane >> 4;

  // chunked XCD swizzle: XCD x gets logical WGs x*128..x*128+127 (one batch's
  // kw slice = 4 MB = one XCD L2)
  const int bid0 = (int)blockIdx.x;
  const int bid  = (bid0 & 7) * 128 + (bid0 >> 3);
  const int b    = bid >> 9;            // / 512
  const int rem  = bid & 511;
  const int q0   = (rem >> 3) * QT;
  const int ks   = rem & 7;
  const int kvbase = ks * KRANGE;

  if (t < KRANGE) s_mask[t] = maskc[b * SS + kvbase + t];

  const float inv_scale = 1.0f / scaleg[0];
  const size_t bh = (size_t)(b * HH + wid);

  // ---- bias staging constants: thread t <-> (qr_s = t>>4, kv pair k2) ----
  const int qr_s = t >> 4;
  const int k2   = (t & 15) << 1;
  const float* bsrc = biasg +
      (((size_t)(b * SS + q0 + qr_s)) * SS + kvbase + k2) * HH;
  float4 pr[2][2];   // [kv in pair][h-half]

#define LOADB(c) do {                                                     \
    const float* _p = bsrc + (size_t)(c) * (CKV * HH);                    \
    pr[0][0] = *(const float4*)(_p);                                      \
    pr[0][1] = *(const float4*)(_p + 4);                                  \
    pr[1][0] = *(const float4*)(_p + HH);                                 \
    pr[1][1] = *(const float4*)(_p + HH + 4);                             \
  } while (0)

#define STAGEB(c) do {                                                    \
    u32* _d = &s_b32[((c) & 1) * BUFSTR + qr_s * LROW + k2];              \
    _Pragma("unroll")                                                     \
    for (int _kv = 0; _kv < 2; ++_kv) {                                   \
      _d[_kv]             = pack_bf16(pr[_kv][0].x, pr[_kv][0].y);        \
      _d[_kv + PLSTR]     = pack_bf16(pr[_kv][0].z, pr[_kv][0].w);        \
      _d[_kv + 2 * PLSTR] = pack_bf16(pr[_kv][1].x, pr[_kv][1].y);        \
      _d[_kv + 3 * PLSTR] = pack_bf16(pr[_kv][1].z, pr[_kv][1].w);        \
    }                                                                     \
  } while (0)

  // ---- k fragment pipeline ----
  short8 kfr[2][4];
  const u16* kwb = kw + (bh * SS + kvbase + l15) * KP + (l4 << 3);

#define LOADK(c) do {                                                     \
    const u16* _k = kwb + (size_t)(c) * (CKV * KP);                       \
    _Pragma("unroll")                                                     \
    for (int _ni = 0; _ni < 2; ++_ni)                                     \
      _Pragma("unroll")                                                   \
      for (int _kf = 0; _kf < 4; ++_kf)                                   \
        kfr[_ni][_kf] = *(const short8*)(_k + _ni * 16 * KP + _kf * 32);  \
  } while (0)

  // ---- prologue: bias c0 load, k c0 load, Q frags, stage c0, bias c1 ----
  LOADB(0);
  LOADK(0);

  short8 afr[2][4];
#pragma unroll
  for (int mi = 0; mi < 2; ++mi)
#pragma unroll
    for (int kf = 0; kf < 4; ++kf) {
      const int row = q0 + mi * 16 + l15;
      afr[mi][kf] = *(const short8*)(qw + (bh * SS + row) * KP + kf * 32 + (l4 << 3));
    }

  STAGEB(0);
  LOADB(1);
  lds_barrier();   // buf0 + s_mask visible

  // epilogue read constants (u16 units): plane = wid>>1, halfword = wid&1
  const u16* sb_base = (const u16*)s_b32;
  const int  sb_off  = (wid >> 1) * (PLSTR * 2) + (wid & 1);

  float* ob = outg + (bh * SS + (size_t)q0) * SS + kvbase + l15;

  for (int c = 0; c < NCH; ++c) {
    // ---- MFMA: 2 x 16-kv tiles, K=128 ----
    f32x4 acc[2][2];
    {
      f32x4 z = {0.f, 0.f, 0.f, 0.f};
      acc[0][0] = z; acc[0][1] = z; acc[1][0] = z; acc[1][1] = z;
    }
#pragma unroll
    for (int kf = 0; kf < 4; ++kf)
#pragma unroll
      for (int ni = 0; ni < 2; ++ni) {
        acc[0][ni] = __builtin_amdgcn_mfma_f32_16x16x32_bf16(afr[0][kf], kfr[ni][kf], acc[0][ni], 0, 0, 0);
        acc[1][ni] = __builtin_amdgcn_mfma_f32_16x16x32_bf16(afr[1][kf], kfr[ni][kf], acc[1][ni], 0, 0, 0);
      }

    // ---- pipelines: k for c+1 (regs just freed), stage bias c+1, load c+2 --
    if (c + 1 < NCH) {
      LOADK(c + 1);
      STAGEB(c + 1);
    }
    if (c + 2 < NCH) LOADB(c + 2);

    // ---- epilogue: bias(LDS bf16) + exp (+ mask), store w' ----
    const u16* sb = sb_base + (c & 1) * (BUFSTR * 2) + sb_off;
#pragma unroll
    for (int ni = 0; ni < 2; ++ni) {
      const int kvl = ni * 16 + l15;
      const float mz = s_mask[c * CKV + kvl] ? 0.0f : 1.0f;
#pragma unroll
      for (int mi = 0; mi < 2; ++mi)
#pragma unroll
        for (int j = 0; j < 4; ++j) {
          const int qr = mi * 16 + (l4 << 2) + j;
          const float bv = bf16_to_f(sb[(qr * LROW + kvl) * 2]);
          const float s  = fmaf(acc[mi][ni][j], inv_scale, bv);
          const float w  = mz * __expf(s);
          ob[(size_t)qr * SS + (size_t)(c * CKV + ni * 16)] = w;
        }
    }
    lds_barrier();   // buf[(c+1)&1] staged; buf[c&1] reads retired
  }
#undef LOADB
#undef STAGEB
#undef LOADK
}

// ---------------- K2: per-row normalize (in place, IC-hot) -----------------
// One wave per row of 2048 floats; 4 rows per 256-thread block.
__global__ __launch_bounds__(256, 4) void norm_kernel(float* __restrict__ outg)
{
  const int wave = (int)threadIdx.x >> 6;
  const int lane = (int)threadIdx.x & 63;
  const size_t row = (size_t)blockIdx.x * 4 + wave;   // < NROWS
  float4* p = (float4*)(outg + row * (size_t)SS);

  float4 v[8];
  float sum = 0.0f;
#pragma unroll
  for (int j = 0; j < 8; ++j) {
    v[j] = p[j * 64 + lane];
    sum += (v[j].x + v[j].y) + (v[j].z + v[j].w);
  }
#pragma unroll
  for (int off = 32; off > 0; off >>= 1) sum += __shfl_xor(sum, off, 64);

  const float inv = (sum > 0.0f) ? (1.0f / sum) : 0.0f;
#pragma unroll
  for (int j = 0; j < 8; ++j) {
    v[j].x *= inv; v[j].y *= inv; v[j].z *= inv; v[j].w *= inv;
    p[j * 64 + lane] = v[j];
  }
}

extern "C" void kernel_launch(void* const* d_in, const int* in_sizes, int n_in,
                              void* d_out, int out_size, void* d_ws, size_t ws_size,
                              hipStream_t stream) {
  const float* qg = (const float*)d_in[0];
  const float* kg = (const float*)d_in[1];
  const float* sc = (const float*)d_in[2];
  const void*  mk = d_in[3];
  const float* bg = (const float*)d_in[4];
  float* out = (float*)d_out;

  // workspace: qw 8MB | kw 8MB | maskc 4KB
  u16* qw  = (u16*)d_ws;
  u16* kw  = qw + (size_t)NROWS * KP;
  u8*  mcw = (u8*)(kw + (size_t)NROWS * KP);

  mask_canon<<<dim3(1), dim3(256), 0, stream>>>(mk, mcw);
  convert_kernel<<<dim3((NROWS * (DD / 4)) / 256), dim3(256), 0, stream>>>(qg, kg, qw, kw);

  const int g1 = BB * (SS / QT) * KSPLIT;  // 1024 WGs
  score_kernel<<<dim3(g1), dim3(512), 0, stream>>>(qw, kw, sc, mcw, bg, out);

  norm_kernel<<<dim3(NROWS / 4), dim3(256), 0, stream>>>(out);
}

// Round 9
// 284.862 us; speedup vs baseline: 1.0542x; 1.0542x over previous
//
#include <hip/hip_runtime.h>
#include <cstdint>
#include <cstddef>

// (B,H,S,Dh) = (2, 8, 2048, 64), all float32 in/out.
#define BB 2
#define HH 8
#define SS 2048
#define DD 64
#define KP 128                 // bf16 hi|lo concatenated along k-dim
#define QT 32                  // q rows per WG
#define KSPLIT 8
#define KRANGE (SS / KSPLIT)   // 256 kv per WG
#define CKV 16                 // kv per chunk (one MFMA tile)
#define NCH (KRANGE / CKV)     // 16 chunks
#define LROW 20                // LDS row stride in u32 (16 kv + pad, 16B-aligned)
#define PLANE (QT * LROW)      // 640 u32 per h-pair plane
#define BUFSTR (4 * PLANE)     // 2560 u32 per buffer
#define NROWS (BB * HH * SS)   // 32768 (b,h,row) triples

typedef short short8 __attribute__((ext_vector_type(8)));
typedef float f32x4  __attribute__((ext_vector_type(4)));
typedef unsigned int u32x4 __attribute__((ext_vector_type(4)));
using u16 = unsigned short;
using u32 = unsigned int;
using u8  = unsigned char;

__device__ inline u16 bf16_rne(float f) {
  u32 u = __builtin_bit_cast(u32, f);
  u32 r = (u + 0x7FFFu + ((u >> 16) & 1u)) >> 16;
  return (u16)r;
}
__device__ inline float bf16_to_f(u16 h) {
  u32 u = ((u32)h) << 16;
  return __builtin_bit_cast(float, u);
}
__device__ inline u32 pack_bf16(float a, float b) {
  return (u32)bf16_rne(a) | ((u32)bf16_rne(b) << 16);
}

// Barrier draining ONLY the LDS queue — __syncthreads would also drain
// vmcnt(0), killing in-flight HBM bias / L2 k prefetches (m97 drain).
__device__ __forceinline__ void lds_barrier() {
  __builtin_amdgcn_sched_barrier(0);
  asm volatile("s_waitcnt lgkmcnt(0)" ::: "memory");
  __builtin_amdgcn_s_barrier();
  __builtin_amdgcn_sched_barrier(0);
}

// ---------------- K_mask: canonicalize mask -> u8[B*S] ---------------------
__global__ __launch_bounds__(256) void mask_canon(
    const void* __restrict__ maskg, u8* __restrict__ mc)
{
  __shared__ int sf, su;
  const int t = (int)threadIdx.x;
  if (t == 0) { sf = 0; su = 0; }
  __syncthreads();
  const u32* mw = (const u32*)maskg;
  int f = 0, u = 0;
  for (int i = t; i < 1024; i += 256) {   // 4KB scan: valid for all encodings
    u32 w = mw[i];
    if (w == 0x3F800000u) f = 1;
    if (w > 1u && w != 0x3F800000u) u = 1;
  }
  if (f) sf = 1;
  if (u) su = 1;
  __syncthreads();
  const int mode = sf ? 2 : (su ? 1 : 0);
  for (int i = t; i < BB * SS; i += 256) {
    u8 m;
    if (mode == 2)      m = (((const float*)maskg)[i] != 0.0f) ? 1 : 0;
    else if (mode == 1) m = (((const u8*)maskg)[i] != 0) ? 1 : 0;
    else                m = (((const int*)maskg)[i] != 0) ? 1 : 0;
    mc[i] = m;
  }
}

// ---------------- K0: f32 -> bf16 hi|lo (K=64 -> K=128) --------------------
__global__ __launch_bounds__(256) void convert_kernel(
    const float* __restrict__ q, const float* __restrict__ k,
    u16* __restrict__ qw, u16* __restrict__ kw)
{
  const int i   = (int)(blockIdx.x * 256 + threadIdx.x);  // float4 index
  const int row = i >> 4;
  const int c4  = (i & 15) << 2;

  const float4 qv = *(const float4*)(q + (size_t)i * 4);
  const float4 kv = *(const float4*)(k + (size_t)i * 4);

  u16 qh[4], ql[4], kh[4], kl[4];
  {
    const float qa[4] = {qv.x, qv.y, qv.z, qv.w};
    const float ka[4] = {kv.x, kv.y, kv.z, kv.w};
#pragma unroll
    for (int j = 0; j < 4; ++j) {
      qh[j] = bf16_rne(qa[j]);
      ql[j] = bf16_rne(qa[j] - bf16_to_f(qh[j]));
      kh[j] = bf16_rne(ka[j]);
      kl[j] = bf16_rne(ka[j] - bf16_to_f(kh[j]));
    }
  }

  uint2 qhi, qlo, khi, klo;
  qhi.x = (u32)qh[0] | ((u32)qh[1] << 16); qhi.y = (u32)qh[2] | ((u32)qh[3] << 16);
  qlo.x = (u32)ql[0] | ((u32)ql[1] << 16); qlo.y = (u32)ql[2] | ((u32)ql[3] << 16);
  khi.x = (u32)kh[0] | ((u32)kh[1] << 16); khi.y = (u32)kh[2] | ((u32)kh[3] << 16);
  klo.x = (u32)kl[0] | ((u32)kl[1] << 16); klo.y = (u32)kl[2] | ((u32)kl[3] << 16);

  const size_t base = (size_t)row * KP + c4;
  *(uint2*)(qw + base)      = qhi;
  *(uint2*)(qw + base + DD) = qlo;
  *(uint2*)(kw + base)      = khi;
  *(uint2*)(kw + base + DD) = klo;
}

// ---------------- K1: scores + bias + exp -> w' (unnormalized) -------------
// WG = 512 = 8 waves = 8 heads, same (b, q-tile 32, kv-range 256).
// SWAPPED MFMA: mfma(A=k, B=q) => lane owns q = q0+mi*16+l15,
// kv = c*16 + l4*4 + j (4 consecutive) -> float4 stores, b128 bias reads.
// Bias dbuf in LDS, bf16-packed (2 heads/u32), plane per h-pair, row pad 20.
// One lgkm-only barrier per chunk; k-frags double-buffered in registers.
__global__ __launch_bounds__(512, 2) void score_kernel(
    const u16* __restrict__ qw, const u16* __restrict__ kw,
    const float* __restrict__ scaleg, const u8* __restrict__ maskc,
    const float* __restrict__ biasg, float* __restrict__ outg)
{
  __shared__ u32 s_b32[2 * BUFSTR];      // 20.5 KB
  __shared__ u32 s_mask32[KRANGE / 4];   // 256 mask bytes as u32

  const int t    = (int)threadIdx.x;
  const int wid  = t >> 6;        // wave = head
  const int lane = t & 63;
  const int l15  = lane & 15;
  const int l4   = lane >> 4;

  const int bid = (int)blockIdx.x;
  const int b   = bid / ((SS / QT) * KSPLIT);
  const int rem = bid % ((SS / QT) * KSPLIT);
  const int q0     = (rem / KSPLIT) * QT;
  const int ks     = rem % KSPLIT;
  const int kvbase = ks * KRANGE;

  if (t < KRANGE / 4)
    s_mask32[t] = *(const u32*)(maskc + b * SS + kvbase + t * 4);

  const float inv_scale = 1.0f / scaleg[0];
  const size_t bh = (size_t)(b * HH + wid);

  // ---- bias staging constants: thread t <-> (qr_s = t>>4, kv_s = t&15) ----
  const int qr_s = t >> 4;
  const int kv_s = t & 15;
  const float* bsrc = biasg +
      (((size_t)(b * SS + q0 + qr_s)) * SS + kvbase + kv_s) * HH;
  float4 pA, pB;   // heads 0-3 / 4-7 of one (qr_s, kv) for the staged chunk

#define LOADB(c) do {                                                     \
    const float* _p = bsrc + (size_t)(c) * (CKV * HH);                    \
    pA = *(const float4*)(_p);                                            \
    pB = *(const float4*)(_p + 4);                                        \
  } while (0)

#define STAGEB(c) do {                                                    \
    u32* _d = &s_b32[((c) & 1) * BUFSTR + qr_s * LROW + kv_s];            \
    _d[0]         = pack_bf16(pA.x, pA.y);                                \
    _d[PLANE]     = pack_bf16(pA.z, pA.w);                                \
    _d[2 * PLANE] = pack_bf16(pB.x, pB.y);                                \
    _d[3 * PLANE] = pack_bf16(pB.z, pB.w);                                \
  } while (0)

  // ---- k fragment pipeline (explicit A/B register sets, rule #20) ----
  const u16* kwb = kw + (bh * SS + kvbase + l15) * KP + (l4 << 3);
#define LOADK(dst, c) do {                                                \
    const u16* _k = kwb + (size_t)(c) * (CKV * KP);                       \
    _Pragma("unroll")                                                     \
    for (int _kf = 0; _kf < 4; ++_kf)                                     \
      dst[_kf] = *(const short8*)(_k + _kf * 32);                         \
  } while (0)

  short8 kfrA[4], kfrB[4];

  // ---- prologue ----
  LOADB(0);
  LOADK(kfrA, 0);

  short8 afr[2][4];
#pragma unroll
  for (int mi = 0; mi < 2; ++mi)
#pragma unroll
    for (int kf = 0; kf < 4; ++kf) {
      const int row = q0 + mi * 16 + l15;
      afr[mi][kf] = *(const short8*)(qw + (bh * SS + row) * KP + kf * 32 + (l4 << 3));
    }

  STAGEB(0);
  LOADB(1);
  lds_barrier();   // buf0 + s_mask visible

  const int hsh = (wid & 1) * 16;              // halfword select within u32
  const u32* sbp = s_b32 + (wid >> 1) * PLANE; // this head-pair's plane
  // output: lane owns rows q0+mi*16+l15, kv run l4*4.. within chunk
  float* ob0 = outg + (bh * SS + (size_t)(q0 + l15)) * SS + kvbase + l4 * 4;
  float* ob1 = ob0 + (size_t)16 * SS;

#define CHUNK(KCUR, KNXT, c) do {                                         \
    f32x4 acc0 = {0.f, 0.f, 0.f, 0.f};                                    \
    f32x4 acc1 = {0.f, 0.f, 0.f, 0.f};                                    \
    _Pragma("unroll")                                                     \
    for (int _kf = 0; _kf < 4; ++_kf) {                                   \
      acc0 = __builtin_amdgcn_mfma_f32_16x16x32_bf16(KCUR[_kf], afr[0][_kf], acc0, 0, 0, 0); \
      acc1 = __builtin_amdgcn_mfma_f32_16x16x32_bf16(KCUR[_kf], afr[1][_kf], acc1, 0, 0, 0); \
    }                                                                     \
    if ((c) + 1 < NCH) { LOADK(KNXT, (c) + 1); STAGEB((c) + 1); }         \
    if ((c) + 2 < NCH) LOADB((c) + 2);                                    \
    const u32 mword = s_mask32[((c) << 2) + l4];                          \
    const u32* _sb = sbp + ((c) & 1) * BUFSTR + l4 * 4;                   \
    const u32x4 bw0 = *(const u32x4*)(_sb + l15 * LROW);                  \
    const u32x4 bw1 = *(const u32x4*)(_sb + (l15 + 16) * LROW);           \
    float4 wv0, wv1;                                                      \
    _Pragma("unroll")                                                     \
    for (int _j = 0; _j < 4; ++_j) {                                      \
      const float _mz = ((mword >> (8 * _j)) & 0xFFu) ? 0.0f : 1.0f;      \
      const float _b0 = bf16_to_f((u16)(bw0[_j] >> hsh));                 \
      const float _b1 = bf16_to_f((u16)(bw1[_j] >> hsh));                 \
      const float _s0 = fmaf(acc0[_j], inv_scale, _b0);                   \
      const float _s1 = fmaf(acc1[_j], inv_scale, _b1);                   \
      ((float*)&wv0)[_j] = _mz * __expf(_s0);                             \
      ((float*)&wv1)[_j] = _mz * __expf(_s1);                             \
    }                                                                     \
    *(float4*)(ob0 + (size_t)(c) * CKV) = wv0;                            \
    *(float4*)(ob1 + (size_t)(c) * CKV) = wv1;                            \
    lds_barrier();                                                        \
  } while (0)

#pragma unroll 1
  for (int c = 0; c < NCH; c += 2) {
    CHUNK(kfrA, kfrB, c);
    CHUNK(kfrB, kfrA, c + 1);
  }
#undef CHUNK
#undef LOADK
#undef STAGEB
#undef LOADB
}

// ---------------- K2: per-row normalize (in place, L3-hot) -----------------
__global__ __launch_bounds__(256, 4) void norm_kernel(float* __restrict__ outg)
{
  const int wave = (int)threadIdx.x >> 6;
  const int lane = (int)threadIdx.x & 63;
  const size_t row = (size_t)blockIdx.x * 4 + wave;   // < NROWS
  float4* p = (float4*)(outg + row * (size_t)SS);

  float4 v[8];
  float sum = 0.0f;
#pragma unroll
  for (int j = 0; j < 8; ++j) {
    v[j] = p[j * 64 + lane];
    sum += (v[j].x + v[j].y) + (v[j].z + v[j].w);
  }
#pragma unroll
  for (int off = 32; off > 0; off >>= 1) sum += __shfl_xor(sum, off, 64);

  const float inv = (sum > 0.0f) ? (1.0f / sum) : 0.0f;
#pragma unroll
  for (int j = 0; j < 8; ++j) {
    v[j].x *= inv; v[j].y *= inv; v[j].z *= inv; v[j].w *= inv;
    p[j * 64 + lane] = v[j];
  }
}

extern "C" void kernel_launch(void* const* d_in, const int* in_sizes, int n_in,
                              void* d_out, int out_size, void* d_ws, size_t ws_size,
                              hipStream_t stream) {
  const float* qg = (const float*)d_in[0];
  const float* kg = (const float*)d_in[1];
  const float* sc = (const float*)d_in[2];
  const void*  mk = d_in[3];
  const float* bg = (const float*)d_in[4];
  float* out = (float*)d_out;

  // workspace: qw 8MB | kw 8MB | maskc 4KB
  u16* qw  = (u16*)d_ws;
  u16* kw  = qw + (size_t)NROWS * KP;
  u8*  mcw = (u8*)(kw + (size_t)NROWS * KP);

  mask_canon<<<dim3(1), dim3(256), 0, stream>>>(mk, mcw);
  convert_kernel<<<dim3((NROWS * (DD / 4)) / 256), dim3(256), 0, stream>>>(qg, kg, qw, kw);

  const int g1 = BB * (SS / QT) * KSPLIT;  // 1024 WGs
  score_kernel<<<dim3(g1), dim3(512), 0, stream>>>(qw, kw, sc, mcw, bg, out);

  norm_kernel<<<dim3(NROWS / 4), dim3(256), 0, stream>>>(out);
}